// Round 3
// baseline (285.147 us; speedup 1.0000x reference)
//
#include <hip/hip_runtime.h>

typedef __bf16 bf16;
typedef __attribute__((ext_vector_type(8))) __bf16 bf16x8;
typedef __attribute__((ext_vector_type(4))) float floatx4;

#define TOK 2048
#define DD  1024
#define NE  8
#define LDA 40       // padded LDS row stride (bf16): 80 B
#define MAXSLOT 72   // max worklist entries: <=39 routed (BM=64) + 32 shared

__device__ __forceinline__ uint4 pack_bf8(float4 a, float4 b) {
  union { bf16 h[8]; uint4 u; } p;
  p.h[0] = (bf16)a.x; p.h[1] = (bf16)a.y; p.h[2] = (bf16)a.z; p.h[3] = (bf16)a.w;
  p.h[4] = (bf16)b.x; p.h[5] = (bf16)b.y; p.h[6] = (bf16)b.z; p.h[7] = (bf16)b.w;
  return p.u;
}

// ---------------- gate + x->bf16 ----------------
__global__ __launch_bounds__(256) void gate_cvt_kernel(
    const float* __restrict__ x, const float* __restrict__ gate_w,
    const float* __restrict__ gate_b, bf16* __restrict__ x_bf,
    int* __restrict__ eidx, float* __restrict__ ewgt)
{
  const int t = blockIdx.x, tid = threadIdx.x;
  const float4 v = ((const float4*)(x + (size_t)t * DD))[tid];
  union { bf16 h[4]; uint2 u; } pk;
  pk.h[0] = (bf16)v.x; pk.h[1] = (bf16)v.y; pk.h[2] = (bf16)v.z; pk.h[3] = (bf16)v.w;
  ((uint2*)(x_bf + (size_t)t * DD))[tid] = pk.u;

  float acc[NE];
#pragma unroll
  for (int e = 0; e < NE; ++e) acc[e] = 0.f;
  const float vv[4] = {v.x, v.y, v.z, v.w};
#pragma unroll
  for (int i = 0; i < 4; ++i) {
    const int d = tid * 4 + i;
    if (d >= 1) {
#pragma unroll
      for (int e = 0; e < NE; ++e) acc[e] += vv[i] * gate_w[e * (DD - 1) + d - 1];
    }
  }
#pragma unroll
  for (int off = 32; off > 0; off >>= 1) {
#pragma unroll
    for (int e = 0; e < NE; ++e) acc[e] += __shfl_down(acc[e], off);
  }
  __shared__ float red[4][NE];
  const int wid = tid >> 6, lane = tid & 63;
  if (lane == 0) {
#pragma unroll
    for (int e = 0; e < NE; ++e) red[wid][e] = acc[e];
  }
  __syncthreads();
  if (tid == 0) {
    float lg[NE];
#pragma unroll
    for (int e = 0; e < NE; ++e) lg[e] = red[0][e] + red[1][e] + red[2][e] + red[3][e];
    float m = lg[0];
    for (int e = 1; e < NE; ++e) m = fmaxf(m, lg[e]);
    float ex[NE], s = 0.f;
    for (int e = 0; e < NE; ++e) { ex[e] = expf(lg[e] - m); s += ex[e]; }
    const float inv = 1.f / s;
    int best = 0; float bb = ex[0] * inv + gate_b[0];
    for (int e = 1; e < NE; ++e) {
      const float b = ex[e] * inv + gate_b[e];
      if (b > bb) { bb = b; best = e; }
    }
    eidx[t] = best;
    ewgt[t] = ex[best] * inv;
  }
}

// ---------------- routing: count + prefix + scatter + WORKLIST ----------------
__global__ __launch_bounds__(256) void route_kernel(
    const int* __restrict__ eidx, int* __restrict__ perm,
    int* __restrict__ pos_of, int4* __restrict__ wl, int* __restrict__ wl_n)
{
  __shared__ int cnt[NE], off[NE], bas[NE + 1];
  const int tid = threadIdx.x;
  if (tid < NE) cnt[tid] = 0;
  __syncthreads();
  for (int t = tid; t < TOK; t += 256) atomicAdd(&cnt[eidx[t]], 1);
  __syncthreads();
  if (tid == 0) {
    int run = 0;
    for (int e = 0; e < NE; ++e) { bas[e] = run; off[e] = run; run += cnt[e]; }
    bas[NE] = run;
    // compact worklist: routed tiles (BM=64) first, then shared tiles
    int n = 0;
    for (int e = 0; e < NE; ++e)
      for (int r0 = 0; r0 < cnt[e]; r0 += 64) {
        int rows = cnt[e] - r0; if (rows > 64) rows = 64;
        wl[n++] = make_int4(bas[e] + r0, rows, e, 0);
      }
    for (int r0 = 0; r0 < TOK; r0 += 64) wl[n++] = make_int4(r0, 64, NE, 0);
    *wl_n = n;
  }
  __syncthreads();
  for (int t = tid; t < TOK; t += 256) {
    const int e = eidx[t];
    const int p = atomicAdd(&off[e], 1);
    perm[p] = t;
    pos_of[t] = p;
  }
}

// ---------------- mlp1: dual GEMM (W1,W3) + silu-gate + h(bf16) + sumsq ----------------
// flat grid: bid = slot*16 + nt ; BM=64, BN=64 (per matrix)
__global__ __launch_bounds__(256) void mlp1_kernel(
    const bf16* __restrict__ x_bf,
    const float* __restrict__ W1, const float* __restrict__ W3,
    const float* __restrict__ Ws1, const float* __restrict__ Ws3,
    const int* __restrict__ perm, const int4* __restrict__ wl,
    const int* __restrict__ wl_n,
    bf16* __restrict__ h_r, bf16* __restrict__ h_s,
    float* __restrict__ ss_r, float* __restrict__ ss_z)
{
  const int bid = blockIdx.x;
  const int slot = bid >> 4, nt = bid & 15;
  if (slot >= *wl_n) return;
  const int4 wle = wl[slot];
  const int mbase = wle.x, rows = wle.y, eid = wle.z;
  const int tid = threadIdx.x;
  const bool routed = (eid < NE);
  const float* w1p = routed ? W1 + (size_t)eid * 1023 * 1024 : Ws1;
  const float* w3p = routed ? W3 + (size_t)eid * 1023 * 1024 : Ws3;
  bf16* hbuf  = routed ? h_r : h_s;
  float* ssbuf = routed ? ss_r : ss_z;
  const int n0 = nt * 64;

  __shared__ __align__(16) bf16 As[64 * LDA];
  __shared__ __align__(16) bf16 B1s[64 * LDA];
  __shared__ __align__(16) bf16 B3s[64 * LDA];
  __shared__ int toks[64];

  if (tid < 64) {
    int r = tid < rows ? tid : rows - 1;
    toks[tid] = routed ? perm[mbase + r] : (mbase + r);
  }
  __syncthreads();

  const int arow = tid >> 2, acol = (tid & 3) * 8;
  const bf16* aptr = x_bf + (size_t)toks[arow] * DD + acol;
  bf16* const alds = As + arow * LDA + acol;

  const int brow = tid >> 2, bcol = (tid & 3) * 8;
  int bn = n0 + brow; if (bn > 1022) bn = 1022;
  const float* b1ptr = w1p + (size_t)bn * 1024 + bcol;
  const float* b3ptr = w3p + (size_t)bn * 1024 + bcol;
  bf16* const b1lds = B1s + brow * LDA + bcol;
  bf16* const b3lds = B3s + brow * LDA + bcol;

  const int wid = tid >> 6, lane = tid & 63;
  const int wc = wid * 16;
  const int lrow = lane & 15, quad = lane >> 4;

  const floatx4 fz = {0.f, 0.f, 0.f, 0.f};
  floatx4 acc1[4], acc3[4];
#pragma unroll
  for (int mi = 0; mi < 4; ++mi) { acc1[mi] = fz; acc3[mi] = fz; }

  uint4  a0  = *(const uint4*)(aptr);
  float4 f10 = *(const float4*)(b1ptr);
  float4 f11 = *(const float4*)(b1ptr + 4);
  float4 f30 = *(const float4*)(b3ptr);
  float4 f31 = *(const float4*)(b3ptr + 4);

  for (int k0 = 0; k0 < 1024; k0 += 32) {
    __syncthreads();
    *(uint4*)alds  = a0;
    *(uint4*)b1lds = pack_bf8(f10, f11);
    *(uint4*)b3lds = pack_bf8(f30, f31);
    __syncthreads();
    const int kn = (k0 + 32 < 1024) ? (k0 + 32) : 0;
    a0  = *(const uint4*)(aptr + kn);
    f10 = *(const float4*)(b1ptr + kn);
    f11 = *(const float4*)(b1ptr + kn + 4);
    f30 = *(const float4*)(b3ptr + kn);
    f31 = *(const float4*)(b3ptr + kn + 4);

    bf16x8 af[4], b1f, b3f;
#pragma unroll
    for (int mi = 0; mi < 4; ++mi)
      af[mi] = *(const bf16x8*)(As + (mi * 16 + lrow) * LDA + quad * 8);
    b1f = *(const bf16x8*)(B1s + (wc + lrow) * LDA + quad * 8);
    b3f = *(const bf16x8*)(B3s + (wc + lrow) * LDA + quad * 8);
#pragma unroll
    for (int mi = 0; mi < 4; ++mi) {
      acc1[mi] = __builtin_amdgcn_mfma_f32_16x16x32_bf16(af[mi], b1f, acc1[mi], 0, 0, 0);
      acc3[mi] = __builtin_amdgcn_mfma_f32_16x16x32_bf16(af[mi], b3f, acc3[mi], 0, 0, 0);
    }
  }

  const int n = n0 + wc + lrow;
#pragma unroll
  for (int mi = 0; mi < 4; ++mi) {
#pragma unroll
    for (int r = 0; r < 4; ++r) {
      const int row = mi * 16 + quad * 4 + r;
      const bool ok = (row < rows) && (n < 1023);
      const float s1 = acc1[mi][r];
      const float s3 = acc3[mi][r];
      const float sp = (s1 / (1.f + __expf(-s1))) * s3;
      float ssum = ok ? sp * sp : 0.f;
      if (ok) hbuf[(size_t)(mbase + row) * 1024 + 1 + n] = (bf16)sp;
      ssum += __shfl_xor(ssum, 1);
      ssum += __shfl_xor(ssum, 2);
      ssum += __shfl_xor(ssum, 4);
      ssum += __shfl_xor(ssum, 8);
      if (lrow == 0 && row < rows) atomicAdd(ssbuf + mbase + row, ssum);
    }
  }
}

// ---------------- h[:,0] = sqrt(sumsq + 1) ----------------
__global__ __launch_bounds__(256) void finalize_t_kernel(
    const float* __restrict__ ss_r, const float* __restrict__ ss_z,
    bf16* __restrict__ h_r, bf16* __restrict__ h_s)
{
  const int i = blockIdx.x * 256 + threadIdx.x;
  if (i < TOK) {
    h_r[(size_t)i * 1024] = (bf16)sqrtf(ss_r[i] + 1.0f);
    h_s[(size_t)i * 1024] = (bf16)sqrtf(ss_z[i] + 1.0f);
  }
}

// ---------------- mlp2: o = h @ W2^T (fp32 out) + sumsq ----------------
// flat grid: bid = slot*16 + nt ; BM=64, BN=64
__global__ __launch_bounds__(256) void mlp2_kernel(
    const bf16* __restrict__ h_r, const bf16* __restrict__ h_s,
    const float* __restrict__ W2, const float* __restrict__ Ws2,
    const int4* __restrict__ wl, const int* __restrict__ wl_n,
    float* __restrict__ o_r, float* __restrict__ o_s,
    float* __restrict__ ss_or, float* __restrict__ ss_oz)
{
  const int bid = blockIdx.x;
  const int slot = bid >> 4, nt = bid & 15;
  if (slot >= *wl_n) return;
  const int4 wle = wl[slot];
  const int mbase = wle.x, rows = wle.y, eid = wle.z;
  const int tid = threadIdx.x;
  const bool routed = (eid < NE);
  const float* wp = routed ? W2 + (size_t)eid * 1023 * 1024 : Ws2;
  const bf16* abuf = routed ? h_r : h_s;
  float* obuf  = routed ? o_r : o_s;
  float* ssbuf = routed ? ss_or : ss_oz;
  const int n0 = nt * 64;

  __shared__ __align__(16) bf16 As[64 * LDA];
  __shared__ __align__(16) bf16 Bs[64 * LDA];

  const int arow = tid >> 2, acol = (tid & 3) * 8;
  const int ar = arow < rows ? arow : rows - 1;
  const bf16* aptr = abuf + (size_t)(mbase + ar) * 1024 + acol;
  bf16* const alds = As + arow * LDA + acol;

  const int brow = tid >> 2, bcol = (tid & 3) * 8;
  int bn = n0 + brow; if (bn > 1022) bn = 1022;
  const float* bptr = wp + (size_t)bn * 1024 + bcol;
  bf16* const blds = Bs + brow * LDA + bcol;

  const int wid = tid >> 6, lane = tid & 63;
  const int wc = wid * 16;
  const int lrow = lane & 15, quad = lane >> 4;

  const floatx4 fz = {0.f, 0.f, 0.f, 0.f};
  floatx4 acc[4];
#pragma unroll
  for (int mi = 0; mi < 4; ++mi) acc[mi] = fz;

  uint4  a0 = *(const uint4*)(aptr);
  float4 f0 = *(const float4*)(bptr);
  float4 f1 = *(const float4*)(bptr + 4);

  for (int k0 = 0; k0 < 1024; k0 += 32) {
    __syncthreads();
    *(uint4*)alds = a0;
    *(uint4*)blds = pack_bf8(f0, f1);
    __syncthreads();
    const int kn = (k0 + 32 < 1024) ? (k0 + 32) : 0;
    a0 = *(const uint4*)(aptr + kn);
    f0 = *(const float4*)(bptr + kn);
    f1 = *(const float4*)(bptr + kn + 4);

    bf16x8 af[4], bfr;
#pragma unroll
    for (int mi = 0; mi < 4; ++mi)
      af[mi] = *(const bf16x8*)(As + (mi * 16 + lrow) * LDA + quad * 8);
    bfr = *(const bf16x8*)(Bs + (wc + lrow) * LDA + quad * 8);
#pragma unroll
    for (int mi = 0; mi < 4; ++mi)
      acc[mi] = __builtin_amdgcn_mfma_f32_16x16x32_bf16(af[mi], bfr, acc[mi], 0, 0, 0);
  }

  const int n = n0 + wc + lrow;
#pragma unroll
  for (int mi = 0; mi < 4; ++mi) {
#pragma unroll
    for (int r = 0; r < 4; ++r) {
      const int row = mi * 16 + quad * 4 + r;
      const bool ok = (row < rows) && (n < 1023);
      const float v = acc[mi][r];
      float ssum = ok ? v * v : 0.f;
      if (ok) obuf[(size_t)(mbase + row) * 1024 + n] = v;
      ssum += __shfl_xor(ssum, 1);
      ssum += __shfl_xor(ssum, 2);
      ssum += __shfl_xor(ssum, 4);
      ssum += __shfl_xor(ssum, 8);
      if (lrow == 0 && row < rows) atomicAdd(ssbuf + mbase + row, ssum);
    }
  }
}

// ---------------- final LResNet combine + Lorentz normalize ----------------
__global__ __launch_bounds__(256) void combine_kernel(
    const float* __restrict__ o_r, const float* __restrict__ o_s,
    const float* __restrict__ ss_or, const float* __restrict__ ss_oz,
    const int* __restrict__ pos_of, const float* __restrict__ wgt,
    float* __restrict__ out)
{
  const int t = blockIdx.x, tid = threadIdx.x;
  const int p = pos_of[t];
  const float w = wgt[t];
  const float4 oz = ((const float4*)(o_s + (size_t)t * 1024))[tid];
  const float4 oe = ((const float4*)(o_r + (size_t)p * 1024))[tid];
  const float tw = 2.f * w;
  float c0 = oz.x + tw * oe.x;
  float c1 = oz.y + tw * oe.y;
  float c2 = oz.z + tw * oe.z;
  float c3 = (tid == 255) ? 0.f : (oz.w + tw * oe.w);  // n=1023 is padding
  float ssum = c0 * c0 + c1 * c1 + c2 * c2 + c3 * c3;
#pragma unroll
  for (int off = 32; off > 0; off >>= 1) ssum += __shfl_down(ssum, off);
  __shared__ float rs[4];
  if ((tid & 63) == 0) rs[tid >> 6] = ssum;
  __syncthreads();
  const float space2 = rs[0] + rs[1] + rs[2] + rs[3];
  const float comb0 = sqrtf(ss_oz[t] + 1.f) + 2.f + 2.f * w * sqrtf(ss_or[p] + 1.f);
  const float li = space2 - comb0 * comb0;
  const float inv = 1.f / sqrtf(fmaxf(fabsf(li), 1e-8f));
  float* orow = out + (size_t)t * 1024;
  const int j = 1 + tid * 4;
  orow[j]     = c0 * inv;
  orow[j + 1] = c1 * inv;
  orow[j + 2] = c2 * inv;
  if (tid != 255) orow[j + 3] = c3 * inv;
  if (tid == 0) orow[0] = comb0 * inv;
}

extern "C" void kernel_launch(void* const* d_in, const int* in_sizes, int n_in,
                              void* d_out, int out_size, void* d_ws, size_t ws_size,
                              hipStream_t stream) {
  const float* x      = (const float*)d_in[0];
  const float* gate_w = (const float*)d_in[1];
  const float* gate_b = (const float*)d_in[2];
  const float* W1     = (const float*)d_in[3];
  const float* W3     = (const float*)d_in[4];
  const float* W2     = (const float*)d_in[5];
  const float* Ws1    = (const float*)d_in[6];
  const float* Ws3    = (const float*)d_in[7];
  const float* Ws2    = (const float*)d_in[8];
  float* out = (float*)d_out;

  char* ws = (char*)d_ws;
  size_t off = 0;
  auto alloc = [&](size_t bytes) {
    void* p = ws + off;
    off += (bytes + 255) & ~(size_t)255;
    return p;
  };
  bf16*  x_bf = (bf16*) alloc((size_t)TOK * 1024 * 2);
  bf16*  h_r  = (bf16*) alloc((size_t)TOK * 1024 * 2);
  bf16*  h_s  = (bf16*) alloc((size_t)TOK * 1024 * 2);
  float* o_r  = (float*)alloc((size_t)TOK * 1024 * 4);
  float* o_s  = (float*)alloc((size_t)TOK * 1024 * 4);
  float* ss   = (float*)alloc((size_t)4 * TOK * 4);  // ss_r, ss_z, ss_or, ss_oz
  int*   eidx = (int*)  alloc((size_t)TOK * 4);
  float* ewgt = (float*)alloc((size_t)TOK * 4);
  int*   perm = (int*)  alloc((size_t)TOK * 4);
  int*   posf = (int*)  alloc((size_t)TOK * 4);
  int4*  wl   = (int4*) alloc((size_t)MAXSLOT * 16);
  int*   wln  = (int*)  alloc(16);

  float* ss_r  = ss;
  float* ss_z  = ss + TOK;
  float* ss_or = ss + 2 * TOK;
  float* ss_oz = ss + 3 * TOK;

  hipMemsetAsync(ss, 0, (size_t)4 * TOK * 4, stream);
  gate_cvt_kernel<<<TOK, 256, 0, stream>>>(x, gate_w, gate_b, x_bf, eidx, ewgt);
  route_kernel<<<1, 256, 0, stream>>>(eidx, perm, posf, wl, wln);
  mlp1_kernel<<<MAXSLOT * 16, 256, 0, stream>>>(x_bf, W1, W3, Ws1, Ws3, perm, wl, wln,
                                                h_r, h_s, ss_r, ss_z);
  finalize_t_kernel<<<8, 256, 0, stream>>>(ss_r, ss_z, h_r, h_s);
  mlp2_kernel<<<MAXSLOT * 16, 256, 0, stream>>>(h_r, h_s, W2, Ws2, wl, wln,
                                                o_r, o_s, ss_or, ss_oz);
  combine_kernel<<<TOK, 256, 0, stream>>>(o_r, o_s, ss_or, ss_oz, posf, ewgt, out);
}

// Round 4
// 283.492 us; speedup vs baseline: 1.0058x; 1.0058x over previous
//
#include <hip/hip_runtime.h>

typedef __bf16 bf16;
typedef __attribute__((ext_vector_type(8))) __bf16 bf16x8;
typedef __attribute__((ext_vector_type(4))) float floatx4;

#define TOK 2048
#define DD  1024
#define NE  8
#define LDA 40       // padded LDS row stride (bf16): 80 B
#define MAXSLOT 72   // max worklist entries: <=39 routed (BM=64) + 32 shared

__device__ __forceinline__ uint4 pack_bf8(float4 a, float4 b) {
  union { bf16 h[8]; uint4 u; } p;
  p.h[0] = (bf16)a.x; p.h[1] = (bf16)a.y; p.h[2] = (bf16)a.z; p.h[3] = (bf16)a.w;
  p.h[4] = (bf16)b.x; p.h[5] = (bf16)b.y; p.h[6] = (bf16)b.z; p.h[7] = (bf16)b.w;
  return p.u;
}

// ---------------- gate + x->bf16 ----------------
__global__ __launch_bounds__(256) void gate_cvt_kernel(
    const float* __restrict__ x, const float* __restrict__ gate_w,
    const float* __restrict__ gate_b, bf16* __restrict__ x_bf,
    int* __restrict__ eidx, float* __restrict__ ewgt)
{
  const int t = blockIdx.x, tid = threadIdx.x;
  const float4 v = ((const float4*)(x + (size_t)t * DD))[tid];
  union { bf16 h[4]; uint2 u; } pk;
  pk.h[0] = (bf16)v.x; pk.h[1] = (bf16)v.y; pk.h[2] = (bf16)v.z; pk.h[3] = (bf16)v.w;
  ((uint2*)(x_bf + (size_t)t * DD))[tid] = pk.u;

  float acc[NE];
#pragma unroll
  for (int e = 0; e < NE; ++e) acc[e] = 0.f;
  const float vv[4] = {v.x, v.y, v.z, v.w};
#pragma unroll
  for (int i = 0; i < 4; ++i) {
    const int d = tid * 4 + i;
    if (d >= 1) {
#pragma unroll
      for (int e = 0; e < NE; ++e) acc[e] += vv[i] * gate_w[e * (DD - 1) + d - 1];
    }
  }
#pragma unroll
  for (int off = 32; off > 0; off >>= 1) {
#pragma unroll
    for (int e = 0; e < NE; ++e) acc[e] += __shfl_down(acc[e], off);
  }
  __shared__ float red[4][NE];
  const int wid = tid >> 6, lane = tid & 63;
  if (lane == 0) {
#pragma unroll
    for (int e = 0; e < NE; ++e) red[wid][e] = acc[e];
  }
  __syncthreads();
  if (tid == 0) {
    float lg[NE];
#pragma unroll
    for (int e = 0; e < NE; ++e) lg[e] = red[0][e] + red[1][e] + red[2][e] + red[3][e];
    float m = lg[0];
    for (int e = 1; e < NE; ++e) m = fmaxf(m, lg[e]);
    float ex[NE], s = 0.f;
    for (int e = 0; e < NE; ++e) { ex[e] = expf(lg[e] - m); s += ex[e]; }
    const float inv = 1.f / s;
    int best = 0; float bb = ex[0] * inv + gate_b[0];
    for (int e = 1; e < NE; ++e) {
      const float b = ex[e] * inv + gate_b[e];
      if (b > bb) { bb = b; best = e; }
    }
    eidx[t] = best;
    ewgt[t] = ex[best] * inv;
  }
}

// ---------------- routing: count + prefix + scatter + WORKLIST ----------------
__global__ __launch_bounds__(256) void route_kernel(
    const int* __restrict__ eidx, int* __restrict__ perm,
    int* __restrict__ pos_of, int4* __restrict__ wl, int* __restrict__ wl_n)
{
  __shared__ int cnt[NE], off[NE], bas[NE + 1];
  const int tid = threadIdx.x;
  if (tid < NE) cnt[tid] = 0;
  __syncthreads();
  for (int t = tid; t < TOK; t += 256) atomicAdd(&cnt[eidx[t]], 1);
  __syncthreads();
  if (tid == 0) {
    int run = 0;
    for (int e = 0; e < NE; ++e) { bas[e] = run; off[e] = run; run += cnt[e]; }
    bas[NE] = run;
    // compact worklist: routed tiles (BM=64) first, then shared tiles
    int n = 0;
    for (int e = 0; e < NE; ++e)
      for (int r0 = 0; r0 < cnt[e]; r0 += 64) {
        int rows = cnt[e] - r0; if (rows > 64) rows = 64;
        wl[n++] = make_int4(bas[e] + r0, rows, e, 0);
      }
    for (int r0 = 0; r0 < TOK; r0 += 64) wl[n++] = make_int4(r0, 64, NE, 0);
    *wl_n = n;
  }
  __syncthreads();
  for (int t = tid; t < TOK; t += 256) {
    const int e = eidx[t];
    const int p = atomicAdd(&off[e], 1);
    perm[p] = t;
    pos_of[t] = p;
  }
}

// ---------------- mlp1: dual GEMM (W1,W3) + silu-gate + h(bf16) + sumsq ----------------
// flat grid: bid = slot*16 + nt ; BM=64, BN=64 (per matrix)
// K-loop: LDS double-buffer, ONE barrier/iter, VGPR prefetch depth 2.
__global__ __launch_bounds__(256) void mlp1_kernel(
    const bf16* __restrict__ x_bf,
    const float* __restrict__ W1, const float* __restrict__ W3,
    const float* __restrict__ Ws1, const float* __restrict__ Ws3,
    const int* __restrict__ perm, const int4* __restrict__ wl,
    const int* __restrict__ wl_n,
    bf16* __restrict__ h_r, bf16* __restrict__ h_s,
    float* __restrict__ ss_r, float* __restrict__ ss_z)
{
  const int bid = blockIdx.x;
  const int slot = bid >> 4, nt = bid & 15;
  if (slot >= *wl_n) return;
  const int4 wle = wl[slot];
  const int mbase = wle.x, rows = wle.y, eid = wle.z;
  const int tid = threadIdx.x;
  const bool routed = (eid < NE);
  const float* w1p = routed ? W1 + (size_t)eid * 1023 * 1024 : Ws1;
  const float* w3p = routed ? W3 + (size_t)eid * 1023 * 1024 : Ws3;
  bf16* hbuf  = routed ? h_r : h_s;
  float* ssbuf = routed ? ss_r : ss_z;
  const int n0 = nt * 64;

  __shared__ __align__(16) bf16 As[2][64 * LDA];
  __shared__ __align__(16) bf16 B1s[2][64 * LDA];
  __shared__ __align__(16) bf16 B3s[2][64 * LDA];
  __shared__ int toks[64];

  if (tid < 64) {
    int r = tid < rows ? tid : rows - 1;
    toks[tid] = routed ? perm[mbase + r] : (mbase + r);
  }
  __syncthreads();

  const int arow = tid >> 2, acol = (tid & 3) * 8;
  const bf16* aptr = x_bf + (size_t)toks[arow] * DD + acol;
  const int aoff = arow * LDA + acol;

  const int brow = tid >> 2, bcol = (tid & 3) * 8;
  int bn = n0 + brow; if (bn > 1022) bn = 1022;
  const float* b1ptr = w1p + (size_t)bn * 1024 + bcol;
  const float* b3ptr = w3p + (size_t)bn * 1024 + bcol;
  const int boff = brow * LDA + bcol;

  const int wid = tid >> 6, lane = tid & 63;
  const int wc = wid * 16;
  const int lrow = lane & 15, quad = lane >> 4;

  const floatx4 fz = {0.f, 0.f, 0.f, 0.f};
  floatx4 acc1[4], acc3[4];
#pragma unroll
  for (int mi = 0; mi < 4; ++mi) { acc1[mi] = fz; acc3[mi] = fz; }

  // two prefetch register sets (depth 2)
  uint4  ra0, ra1; float4 r10_0, r11_0, r30_0, r31_0, r10_1, r11_1, r30_1, r31_1;
  // tile 0 -> set0
  ra0 = *(const uint4*)(aptr);
  r10_0 = *(const float4*)(b1ptr);     r11_0 = *(const float4*)(b1ptr + 4);
  r30_0 = *(const float4*)(b3ptr);     r31_0 = *(const float4*)(b3ptr + 4);
  // tile 1 -> set1
  ra1 = *(const uint4*)(aptr + 32);
  r10_1 = *(const float4*)(b1ptr + 32); r11_1 = *(const float4*)(b1ptr + 36);
  r30_1 = *(const float4*)(b3ptr + 32); r31_1 = *(const float4*)(b3ptr + 36);
  // stage tile 0 into buf 0
  *(uint4*)(&As[0][aoff])  = ra0;
  *(uint4*)(&B1s[0][boff]) = pack_bf8(r10_0, r11_0);
  *(uint4*)(&B3s[0][boff]) = pack_bf8(r30_0, r31_0);
  // reload set0 with tile 2
  ra0 = *(const uint4*)(aptr + 64);
  r10_0 = *(const float4*)(b1ptr + 64); r11_0 = *(const float4*)(b1ptr + 68);
  r30_0 = *(const float4*)(b3ptr + 64); r31_0 = *(const float4*)(b3ptr + 68);

#define MLP1_STEP(KK, CUR, NXT, RA, R10, R11, R30, R31)                              \
  {                                                                                  \
    __syncthreads();                                                                 \
    bf16x8 af0 = *(const bf16x8*)(&As[CUR][(0 * 16 + lrow) * LDA + quad * 8]);       \
    bf16x8 af1 = *(const bf16x8*)(&As[CUR][(1 * 16 + lrow) * LDA + quad * 8]);       \
    bf16x8 af2 = *(const bf16x8*)(&As[CUR][(2 * 16 + lrow) * LDA + quad * 8]);       \
    bf16x8 af3 = *(const bf16x8*)(&As[CUR][(3 * 16 + lrow) * LDA + quad * 8]);       \
    bf16x8 b1f = *(const bf16x8*)(&B1s[CUR][(wc + lrow) * LDA + quad * 8]);          \
    bf16x8 b3f = *(const bf16x8*)(&B3s[CUR][(wc + lrow) * LDA + quad * 8]);          \
    if ((KK) < 31) {                                                                 \
      *(uint4*)(&As[NXT][aoff])  = RA;                                               \
      *(uint4*)(&B1s[NXT][boff]) = pack_bf8(R10, R11);                               \
      *(uint4*)(&B3s[NXT][boff]) = pack_bf8(R30, R31);                               \
      const int kt = ((KK) + 3 < 32 ? (KK) + 3 : 0) * 32;                            \
      RA  = *(const uint4*)(aptr + kt);                                              \
      R10 = *(const float4*)(b1ptr + kt); R11 = *(const float4*)(b1ptr + kt + 4);    \
      R30 = *(const float4*)(b3ptr + kt); R31 = *(const float4*)(b3ptr + kt + 4);    \
    }                                                                                \
    acc1[0] = __builtin_amdgcn_mfma_f32_16x16x32_bf16(af0, b1f, acc1[0], 0, 0, 0);   \
    acc3[0] = __builtin_amdgcn_mfma_f32_16x16x32_bf16(af0, b3f, acc3[0], 0, 0, 0);   \
    acc1[1] = __builtin_amdgcn_mfma_f32_16x16x32_bf16(af1, b1f, acc1[1], 0, 0, 0);   \
    acc3[1] = __builtin_amdgcn_mfma_f32_16x16x32_bf16(af1, b3f, acc3[1], 0, 0, 0);   \
    acc1[2] = __builtin_amdgcn_mfma_f32_16x16x32_bf16(af2, b1f, acc1[2], 0, 0, 0);   \
    acc3[2] = __builtin_amdgcn_mfma_f32_16x16x32_bf16(af2, b3f, acc3[2], 0, 0, 0);   \
    acc1[3] = __builtin_amdgcn_mfma_f32_16x16x32_bf16(af3, b1f, acc1[3], 0, 0, 0);   \
    acc3[3] = __builtin_amdgcn_mfma_f32_16x16x32_bf16(af3, b3f, acc3[3], 0, 0, 0);   \
  }

  for (int k = 0; k < 32; k += 2) {
    // even sub-iter: read buf0, stage set1 -> buf1, reload set1 <- tile k+3
    MLP1_STEP(k,     0, 1, ra1, r10_1, r11_1, r30_1, r31_1);
    // odd sub-iter:  read buf1, stage set0 -> buf0, reload set0 <- tile k+4
    MLP1_STEP(k + 1, 1, 0, ra0, r10_0, r11_0, r30_0, r31_0);
  }
#undef MLP1_STEP

  const int n = n0 + wc + lrow;
#pragma unroll
  for (int mi = 0; mi < 4; ++mi) {
#pragma unroll
    for (int r = 0; r < 4; ++r) {
      const int row = mi * 16 + quad * 4 + r;
      const bool ok = (row < rows) && (n < 1023);
      const float s1 = acc1[mi][r];
      const float s3 = acc3[mi][r];
      const float sp = (s1 / (1.f + __expf(-s1))) * s3;
      float ssum = ok ? sp * sp : 0.f;
      if (ok) hbuf[(size_t)(mbase + row) * 1024 + 1 + n] = (bf16)sp;
      ssum += __shfl_xor(ssum, 1);
      ssum += __shfl_xor(ssum, 2);
      ssum += __shfl_xor(ssum, 4);
      ssum += __shfl_xor(ssum, 8);
      if (lrow == 0 && row < rows) atomicAdd(ssbuf + mbase + row, ssum);
    }
  }
}

// ---------------- h[:,0] = sqrt(sumsq + 1) ----------------
__global__ __launch_bounds__(256) void finalize_t_kernel(
    const float* __restrict__ ss_r, const float* __restrict__ ss_z,
    bf16* __restrict__ h_r, bf16* __restrict__ h_s)
{
  const int i = blockIdx.x * 256 + threadIdx.x;
  if (i < TOK) {
    h_r[(size_t)i * 1024] = (bf16)sqrtf(ss_r[i] + 1.0f);
    h_s[(size_t)i * 1024] = (bf16)sqrtf(ss_z[i] + 1.0f);
  }
}

// ---------------- mlp2: o = h @ W2^T (fp32 out) + sumsq ----------------
// flat grid: bid = slot*16 + nt ; BM=64, BN=64; same pipelined K-loop
__global__ __launch_bounds__(256) void mlp2_kernel(
    const bf16* __restrict__ h_r, const bf16* __restrict__ h_s,
    const float* __restrict__ W2, const float* __restrict__ Ws2,
    const int4* __restrict__ wl, const int* __restrict__ wl_n,
    float* __restrict__ o_r, float* __restrict__ o_s,
    float* __restrict__ ss_or, float* __restrict__ ss_oz)
{
  const int bid = blockIdx.x;
  const int slot = bid >> 4, nt = bid & 15;
  if (slot >= *wl_n) return;
  const int4 wle = wl[slot];
  const int mbase = wle.x, rows = wle.y, eid = wle.z;
  const int tid = threadIdx.x;
  const bool routed = (eid < NE);
  const float* wp = routed ? W2 + (size_t)eid * 1023 * 1024 : Ws2;
  const bf16* abuf = routed ? h_r : h_s;
  float* obuf  = routed ? o_r : o_s;
  float* ssbuf = routed ? ss_or : ss_oz;
  const int n0 = nt * 64;

  __shared__ __align__(16) bf16 As[2][64 * LDA];
  __shared__ __align__(16) bf16 Bs[2][64 * LDA];

  const int arow = tid >> 2, acol = (tid & 3) * 8;
  const int ar = arow < rows ? arow : rows - 1;
  const bf16* aptr = abuf + (size_t)(mbase + ar) * 1024 + acol;
  const int aoff = arow * LDA + acol;

  const int brow = tid >> 2, bcol = (tid & 3) * 8;
  int bn = n0 + brow; if (bn > 1022) bn = 1022;
  const float* bptr = wp + (size_t)bn * 1024 + bcol;
  const int boff = brow * LDA + bcol;

  const int wid = tid >> 6, lane = tid & 63;
  const int wc = wid * 16;
  const int lrow = lane & 15, quad = lane >> 4;

  const floatx4 fz = {0.f, 0.f, 0.f, 0.f};
  floatx4 acc[4];
#pragma unroll
  for (int mi = 0; mi < 4; ++mi) acc[mi] = fz;

  uint4 ra0, ra1; float4 r0_0, r1_0, r0_1, r1_1;
  ra0 = *(const uint4*)(aptr);
  r0_0 = *(const float4*)(bptr);      r1_0 = *(const float4*)(bptr + 4);
  ra1 = *(const uint4*)(aptr + 32);
  r0_1 = *(const float4*)(bptr + 32); r1_1 = *(const float4*)(bptr + 36);
  *(uint4*)(&As[0][aoff]) = ra0;
  *(uint4*)(&Bs[0][boff]) = pack_bf8(r0_0, r1_0);
  ra0 = *(const uint4*)(aptr + 64);
  r0_0 = *(const float4*)(bptr + 64); r1_0 = *(const float4*)(bptr + 68);

#define MLP2_STEP(KK, CUR, NXT, RA, R0, R1)                                          \
  {                                                                                  \
    __syncthreads();                                                                 \
    bf16x8 af0 = *(const bf16x8*)(&As[CUR][(0 * 16 + lrow) * LDA + quad * 8]);       \
    bf16x8 af1 = *(const bf16x8*)(&As[CUR][(1 * 16 + lrow) * LDA + quad * 8]);       \
    bf16x8 af2 = *(const bf16x8*)(&As[CUR][(2 * 16 + lrow) * LDA + quad * 8]);       \
    bf16x8 af3 = *(const bf16x8*)(&As[CUR][(3 * 16 + lrow) * LDA + quad * 8]);       \
    bf16x8 bfr = *(const bf16x8*)(&Bs[CUR][(wc + lrow) * LDA + quad * 8]);           \
    if ((KK) < 31) {                                                                 \
      *(uint4*)(&As[NXT][aoff]) = RA;                                                \
      *(uint4*)(&Bs[NXT][boff]) = pack_bf8(R0, R1);                                  \
      const int kt = ((KK) + 3 < 32 ? (KK) + 3 : 0) * 32;                            \
      RA = *(const uint4*)(aptr + kt);                                               \
      R0 = *(const float4*)(bptr + kt); R1 = *(const float4*)(bptr + kt + 4);        \
    }                                                                                \
    acc[0] = __builtin_amdgcn_mfma_f32_16x16x32_bf16(af0, bfr, acc[0], 0, 0, 0);     \
    acc[1] = __builtin_amdgcn_mfma_f32_16x16x32_bf16(af1, bfr, acc[1], 0, 0, 0);     \
    acc[2] = __builtin_amdgcn_mfma_f32_16x16x32_bf16(af2, bfr, acc[2], 0, 0, 0);     \
    acc[3] = __builtin_amdgcn_mfma_f32_16x16x32_bf16(af3, bfr, acc[3], 0, 0, 0);     \
  }

  for (int k = 0; k < 32; k += 2) {
    MLP2_STEP(k,     0, 1, ra1, r0_1, r1_1);
    MLP2_STEP(k + 1, 1, 0, ra0, r0_0, r1_0);
  }
#undef MLP2_STEP

  const int n = n0 + wc + lrow;
#pragma unroll
  for (int mi = 0; mi < 4; ++mi) {
#pragma unroll
    for (int r = 0; r < 4; ++r) {
      const int row = mi * 16 + quad * 4 + r;
      const bool ok = (row < rows) && (n < 1023);
      const float v = acc[mi][r];
      float ssum = ok ? v * v : 0.f;
      if (ok) obuf[(size_t)(mbase + row) * 1024 + n] = v;
      ssum += __shfl_xor(ssum, 1);
      ssum += __shfl_xor(ssum, 2);
      ssum += __shfl_xor(ssum, 4);
      ssum += __shfl_xor(ssum, 8);
      if (lrow == 0 && row < rows) atomicAdd(ssbuf + mbase + row, ssum);
    }
  }
}

// ---------------- final LResNet combine + Lorentz normalize ----------------
__global__ __launch_bounds__(256) void combine_kernel(
    const float* __restrict__ o_r, const float* __restrict__ o_s,
    const float* __restrict__ ss_or, const float* __restrict__ ss_oz,
    const int* __restrict__ pos_of, const float* __restrict__ wgt,
    float* __restrict__ out)
{
  const int t = blockIdx.x, tid = threadIdx.x;
  const int p = pos_of[t];
  const float w = wgt[t];
  const float4 oz = ((const float4*)(o_s + (size_t)t * 1024))[tid];
  const float4 oe = ((const float4*)(o_r + (size_t)p * 1024))[tid];
  const float tw = 2.f * w;
  float c0 = oz.x + tw * oe.x;
  float c1 = oz.y + tw * oe.y;
  float c2 = oz.z + tw * oe.z;
  float c3 = (tid == 255) ? 0.f : (oz.w + tw * oe.w);  // n=1023 is padding
  float ssum = c0 * c0 + c1 * c1 + c2 * c2 + c3 * c3;
#pragma unroll
  for (int off = 32; off > 0; off >>= 1) ssum += __shfl_down(ssum, off);
  __shared__ float rs[4];
  if ((tid & 63) == 0) rs[tid >> 6] = ssum;
  __syncthreads();
  const float space2 = rs[0] + rs[1] + rs[2] + rs[3];
  const float comb0 = sqrtf(ss_oz[t] + 1.f) + 2.f + 2.f * w * sqrtf(ss_or[p] + 1.f);
  const float li = space2 - comb0 * comb0;
  const float inv = 1.f / sqrtf(fmaxf(fabsf(li), 1e-8f));
  float* orow = out + (size_t)t * 1024;
  const int j = 1 + tid * 4;
  orow[j]     = c0 * inv;
  orow[j + 1] = c1 * inv;
  orow[j + 2] = c2 * inv;
  if (tid != 255) orow[j + 3] = c3 * inv;
  if (tid == 0) orow[0] = comb0 * inv;
}

extern "C" void kernel_launch(void* const* d_in, const int* in_sizes, int n_in,
                              void* d_out, int out_size, void* d_ws, size_t ws_size,
                              hipStream_t stream) {
  const float* x      = (const float*)d_in[0];
  const float* gate_w = (const float*)d_in[1];
  const float* gate_b = (const float*)d_in[2];
  const float* W1     = (const float*)d_in[3];
  const float* W3     = (const float*)d_in[4];
  const float* W2     = (const float*)d_in[5];
  const float* Ws1    = (const float*)d_in[6];
  const float* Ws3    = (const float*)d_in[7];
  const float* Ws2    = (const float*)d_in[8];
  float* out = (float*)d_out;

  char* ws = (char*)d_ws;
  size_t off = 0;
  auto alloc = [&](size_t bytes) {
    void* p = ws + off;
    off += (bytes + 255) & ~(size_t)255;
    return p;
  };
  bf16*  x_bf = (bf16*) alloc((size_t)TOK * 1024 * 2);
  bf16*  h_r  = (bf16*) alloc((size_t)TOK * 1024 * 2);
  bf16*  h_s  = (bf16*) alloc((size_t)TOK * 1024 * 2);
  float* o_r  = (float*)alloc((size_t)TOK * 1024 * 4);
  float* o_s  = (float*)alloc((size_t)TOK * 1024 * 4);
  float* ss   = (float*)alloc((size_t)4 * TOK * 4);  // ss_r, ss_z, ss_or, ss_oz
  int*   eidx = (int*)  alloc((size_t)TOK * 4);
  float* ewgt = (float*)alloc((size_t)TOK * 4);
  int*   perm = (int*)  alloc((size_t)TOK * 4);
  int*   posf = (int*)  alloc((size_t)TOK * 4);
  int4*  wl   = (int4*) alloc((size_t)MAXSLOT * 16);
  int*   wln  = (int*)  alloc(16);

  float* ss_r  = ss;
  float* ss_z  = ss + TOK;
  float* ss_or = ss + 2 * TOK;
  float* ss_oz = ss + 3 * TOK;

  hipMemsetAsync(ss, 0, (size_t)4 * TOK * 4, stream);
  gate_cvt_kernel<<<TOK, 256, 0, stream>>>(x, gate_w, gate_b, x_bf, eidx, ewgt);
  route_kernel<<<1, 256, 0, stream>>>(eidx, perm, posf, wl, wln);
  mlp1_kernel<<<MAXSLOT * 16, 256, 0, stream>>>(x_bf, W1, W3, Ws1, Ws3, perm, wl, wln,
                                                h_r, h_s, ss_r, ss_z);
  finalize_t_kernel<<<8, 256, 0, stream>>>(ss_r, ss_z, h_r, h_s);
  mlp2_kernel<<<MAXSLOT * 16, 256, 0, stream>>>(h_r, h_s, W2, Ws2, wl, wln,
                                                o_r, o_s, ss_or, ss_oz);
  combine_kernel<<<TOK, 256, 0, stream>>>(o_r, o_s, ss_or, ss_oz, posf, ewgt, out);
}